// Round 10
// baseline (2646.890 us; speedup 1.0000x reference)
//
#include <hip/hip_runtime.h>

#define TT 1024
#define BB 64
#define FF 256
#define HH 512

// ---------------------------------------------------------------------------
// Kernel 1: i_n = x @ W_ih^T + b_ih  -> io (= d_out), overwritten in-place by
// the recurrence with h_t.  (unchanged)
// ---------------------------------------------------------------------------
__global__ __launch_bounds__(256) void in_gemm(
    const float* __restrict__ x, const float* __restrict__ Wih,
    const float* __restrict__ bih, float* __restrict__ io)
{
    __shared__ float xs[32][68];
    __shared__ float wst[64][68];

    const int bid = blockIdx.x;
    const int rb = bid >> 3, cb = bid & 7;
    const int m0 = rb * 32, n0 = cb * 64;
    const int t  = threadIdx.x;
    const int ti = t >> 4, tj = t & 15;

    float acc[2][4] = {{0.f,0.f,0.f,0.f},{0.f,0.f,0.f,0.f}};

    for (int k0 = 0; k0 < FF; k0 += 64) {
        {
            int flat = t * 8;
            int row = flat >> 6, col = flat & 63;
            const float* src = &x[(size_t)(m0 + row) * FF + k0 + col];
            float4 a = *(const float4*)&src[0];
            float4 b = *(const float4*)&src[4];
            *(float4*)&xs[row][col]     = a;
            *(float4*)&xs[row][col + 4] = b;
        }
        {
            int j  = t >> 2;
            int kk = (t & 3) * 16;
            const float* src = &Wih[(size_t)(n0 + j) * FF + k0 + kk];
            #pragma unroll
            for (int q = 0; q < 4; ++q) {
                float4 v = *(const float4*)&src[q * 4];
                wst[kk + q*4 + 0][j] = v.x;
                wst[kk + q*4 + 1][j] = v.y;
                wst[kk + q*4 + 2][j] = v.z;
                wst[kk + q*4 + 3][j] = v.w;
            }
        }
        __syncthreads();
        #pragma unroll
        for (int k = 0; k < 64; k += 4) {
            float4 xa = *(const float4*)&xs[ti][k];
            float4 xb = *(const float4*)&xs[ti + 16][k];
            #pragma unroll
            for (int q = 0; q < 4; ++q) {
                float4 wv = *(const float4*)&wst[k + q][tj * 4];
                float xav = (&xa.x)[q], xbv = (&xb.x)[q];
                acc[0][0] = fmaf(xav, wv.x, acc[0][0]);
                acc[0][1] = fmaf(xav, wv.y, acc[0][1]);
                acc[0][2] = fmaf(xav, wv.z, acc[0][2]);
                acc[0][3] = fmaf(xav, wv.w, acc[0][3]);
                acc[1][0] = fmaf(xbv, wv.x, acc[1][0]);
                acc[1][1] = fmaf(xbv, wv.y, acc[1][1]);
                acc[1][2] = fmaf(xbv, wv.z, acc[1][2]);
                acc[1][3] = fmaf(xbv, wv.w, acc[1][3]);
            }
        }
        __syncthreads();
    }

    float4 bv = *(const float4*)&bih[n0 + tj * 4];
    float4 r0 = make_float4(acc[0][0]+bv.x, acc[0][1]+bv.y, acc[0][2]+bv.z, acc[0][3]+bv.w);
    float4 r1 = make_float4(acc[1][0]+bv.x, acc[1][1]+bv.y, acc[1][2]+bv.z, acc[1][3]+bv.w);
    *(float4*)&io[(size_t)(m0 + ti)      * HH + n0 + tj * 4] = r0;
    *(float4*)&io[(size_t)(m0 + ti + 16) * HH + n0 + tj * 4] = r1;
}

// ---------------------------------------------------------------------------
// Kernel 2: ROUND-10 — two interleaved chains per WG.
//
// r9 analysis: step 4440 cy = 2430 VALU (FMA wall 1024 is the fp32 floor)
// + ~2000 exposed L3 RTT (publish->visible + poll detect) + skew. The RTT
// can't shrink; hide it under an INDEPENDENT chain (r8 idea, minus its
// mistake of 4 epilogues on the critical path).
//
// Decomposition: 16 groups x 4 batches x 16 WGs (256 WGs; 84 KB LDS pad ->
// 1 WG/CU). WG owns 32 h-rows = 64 gate-rows; thread = 1 gate-row x 64-k
// slice (W = 64 floats, pinned). Step = phase A (batches c0,c0+1) then
// phase B (c0+2,c0+3):
//   poll(ph) -> stage -> pipelined FMA (128/thread) -> spec-issue other
//   phase's h loads -> deposit red[ph] -> barrier -> wave{0|1} epilogue.
// A's publish latency hides under B's poll+FMA and vice versa.
// Speculative polls are SELF-VALIDATING (epoch-in-mantissa): hit -> free
// detect; miss -> normal poll loop. No parity on red needed: wave0 reads
// red[0](t) before it arrives at B-barrier(t); all red[0](t+1) deposits
// are after B-barrier(t) releases (which needs wave0). Audited likewise
// for red[1]. hst reuse A->B is same-wave, DS ops execute in order.
// ---------------------------------------------------------------------------
#define P8(A,i) "+v"(A[(i)+0]), "+v"(A[(i)+1]), "+v"(A[(i)+2]), "+v"(A[(i)+3]), \
                "+v"(A[(i)+4]), "+v"(A[(i)+5]), "+v"(A[(i)+6]), "+v"(A[(i)+7])

__global__ __launch_bounds__(512, 2) void mgu_rec(
    const float* __restrict__ Whh, const float* __restrict__ bhh,
    float* __restrict__ io, float* __restrict__ hbuf)
{
    const int bid  = blockIdx.x;
    const int sp   = bid >> 4;      // row slice 0..15 (32 h-rows)
    const int g    = bid & 15;      // batch group 0..15
    const int c0   = g * 4;         // 4 batches per group
    const int tid  = threadIdx.x;
    const int w    = tid >> 6;      // wave 0..7 -> 64-wide k-slice
    const int l    = tid & 63;      // lane
    const int gate = l >> 5;        // 0 = f-gate row, 1 = n-gate row
    const int r0   = l & 31;        // row within slice

    __shared__ float hst[2][HH];            // [batch-of-phase][k] (4 KB)
    __shared__ float red[2][8][2][2][32];   // [phase][wave][gate][batch][row] (8 KB)
    __shared__ float lds_pad[18432];        // 72 KB -> total 84 KB > 80 KB
                                            // => 1 WG/CU (no co-scheduling)
    if (tid == 0) { volatile float* vp = lds_pad; vp[0] = 0.f; }

    // --- persistent W: one gate-row, 64-wide k-slice (64 floats) ---
    float Wk[64];
    {
        const int wrow = gate * 512 + sp * 32 + r0;   // row of Whh [2H x H]
        const float* pw = &Whh[(size_t)wrow * HH + w * 64];
        #pragma unroll
        for (int q = 0; q < 16; ++q) {
            float4 a = *(const float4*)&pw[q * 4];
            Wk[q*4+0] = a.x; Wk[q*4+1] = a.y; Wk[q*4+2] = a.z; Wk[q*4+3] = a.w;
        }
    }
    asm volatile("" : P8(Wk,0),  P8(Wk,8),  P8(Wk,16), P8(Wk,24));
    asm volatile("" : P8(Wk,32), P8(Wk,40), P8(Wk,48), P8(Wk,56));

    const int kb = w * 64;   // wave's k-slice base

    // epilogue roles: wave 0 -> phase A, wave 1 -> phase B.
    // lane l -> (batch offset l>>5, row sp*32 + (l&31))
    const bool epi = (w < 2);
    float bfv = 0.f, bnv = 0.f, hprev = 0.f, in_cur = 0.f, in_nxt = 0.f;
    size_t obase = 0;
    if (epi) {
        bfv = bhh[sp * 32 + r0];
        bnv = bhh[512 + sp * 32 + r0];
        const int bb = c0 + (w == 1 ? 2 : 0) + (l >> 5);
        obase = (size_t)bb * HH + sp * 32 + r0;   // + t*BB*HH per step
        in_nxt = io[obase];                        // i_n for t=0
    }

    float sA0 = 0.f, sA1 = 0.f, sB0 = 0.f, sB1 = 0.f;  // speculative h regs

    for (int t = 0; t < TT; ++t) {
        // rotate i_n pipeline (epilogue waves only)
        if (epi) {
            in_cur = in_nxt;
            if (t + 1 < TT) in_nxt = io[obase + (size_t)(t + 1) * BB * HH];
        }

        // ==================== phase A (batches c0, c0+1) ====================
        {
            float v0, v1;
            if (t > 0) {
                const int tr = t - 1;
                const unsigned ep = (unsigned)(((tr >> 2) % 3) + 1);
                const float* a0 = &hbuf[(size_t)(tr & 3) * BB * HH
                                        + (size_t)c0 * HH + kb + l];
                const float* a1 = a0 + HH;
                bool ok = ((__float_as_uint(sA0) & 3u) == ep) &
                          ((__float_as_uint(sA1) & 3u) == ep);
                while (!__all((int)ok)) {
                    sA0 = __hip_atomic_load(a0, __ATOMIC_RELAXED, __HIP_MEMORY_SCOPE_AGENT);
                    sA1 = __hip_atomic_load(a1, __ATOMIC_RELAXED, __HIP_MEMORY_SCOPE_AGENT);
                    ok = ((__float_as_uint(sA0) & 3u) == ep) &
                         ((__float_as_uint(sA1) & 3u) == ep);
                }
                v0 = sA0; v1 = sA1;
            } else { v0 = 0.f; v1 = 0.f; }
            hst[0][kb + l] = v0;
            hst[1][kb + l] = v1;

            float p0 = 0.f, p1 = 0.f;
            {
                float4 h0a = *(const float4*)&hst[0][kb];
                float4 h1a = *(const float4*)&hst[1][kb];
                #pragma unroll
                for (int q = 0; q < 16; ++q) {
                    float4 h0b, h1b;
                    if (q < 15) {
                        h0b = *(const float4*)&hst[0][kb + (q + 1) * 4];
                        h1b = *(const float4*)&hst[1][kb + (q + 1) * 4];
                    }
                    p0 = fmaf(Wk[q*4+0], h0a.x, p0); p1 = fmaf(Wk[q*4+0], h1a.x, p1);
                    p0 = fmaf(Wk[q*4+1], h0a.y, p0); p1 = fmaf(Wk[q*4+1], h1a.y, p1);
                    p0 = fmaf(Wk[q*4+2], h0a.z, p0); p1 = fmaf(Wk[q*4+2], h1a.z, p1);
                    p0 = fmaf(Wk[q*4+3], h0a.w, p0); p1 = fmaf(Wk[q*4+3], h1a.w, p1);
                    if ((q & 3) == 3) __builtin_amdgcn_sched_barrier(0);
                    h0a = h0b; h1a = h1b;
                }
            }

            // speculative pre-issue for phase B's poll (B(t-1)); the loads
            // fly during deposit + barrier + epilogue-A
            if (t > 0) {
                const int tr = t - 1;
                const float* b0 = &hbuf[(size_t)(tr & 3) * BB * HH
                                        + (size_t)(c0 + 2) * HH + kb + l];
                sB0 = __hip_atomic_load(b0,      __ATOMIC_RELAXED, __HIP_MEMORY_SCOPE_AGENT);
                sB1 = __hip_atomic_load(b0 + HH, __ATOMIC_RELAXED, __HIP_MEMORY_SCOPE_AGENT);
            }

            red[0][w][gate][0][r0] = p0;
            red[0][w][gate][1][r0] = p1;
            __syncthreads();

            if (w == 0) {   // epilogue A
                const int b = l >> 5, r = l & 31;
                float fs = 0.f, ns = 0.f;
                #pragma unroll
                for (int ww = 0; ww < 8; ++ww) {
                    fs += red[0][ww][0][b][r];
                    ns += red[0][ww][1][b][r];
                }
                float fg = __builtin_amdgcn_rcpf(1.f + __expf(-(fs + bfv)));
                float e2 = __expf(2.f * (in_cur + fg * (ns + bnv)));
                float nv = 1.f - 2.f * __builtin_amdgcn_rcpf(e2 + 1.f);
                float hn = nv + (1.f - fg) * (hprev - nv);
                hprev = hn;
                const unsigned ep = (unsigned)(((t >> 2) % 3) + 1);
                float ev = __uint_as_float((__float_as_uint(hn) & ~3u) | ep);
                float* dst = &hbuf[(size_t)(t & 3) * BB * HH
                                   + (size_t)(c0 + b) * HH + sp * 32 + r];
                __hip_atomic_store(dst, ev, __ATOMIC_RELAXED, __HIP_MEMORY_SCOPE_AGENT);
                io[obase + (size_t)t * BB * HH] = hn;
            }
        }

        // ==================== phase B (batches c0+2, c0+3) ==================
        {
            float v0, v1;
            if (t > 0) {
                const int tr = t - 1;
                const unsigned ep = (unsigned)(((tr >> 2) % 3) + 1);
                const float* b0 = &hbuf[(size_t)(tr & 3) * BB * HH
                                        + (size_t)(c0 + 2) * HH + kb + l];
                const float* b1 = b0 + HH;
                bool ok = ((__float_as_uint(sB0) & 3u) == ep) &
                          ((__float_as_uint(sB1) & 3u) == ep);
                while (!__all((int)ok)) {
                    sB0 = __hip_atomic_load(b0, __ATOMIC_RELAXED, __HIP_MEMORY_SCOPE_AGENT);
                    sB1 = __hip_atomic_load(b1, __ATOMIC_RELAXED, __HIP_MEMORY_SCOPE_AGENT);
                    ok = ((__float_as_uint(sB0) & 3u) == ep) &
                         ((__float_as_uint(sB1) & 3u) == ep);
                }
                v0 = sB0; v1 = sB1;
            } else { v0 = 0.f; v1 = 0.f; }
            hst[0][kb + l] = v0;   // same-wave reuse: DS ops in order, safe
            hst[1][kb + l] = v1;

            float p0 = 0.f, p1 = 0.f;
            {
                float4 h0a = *(const float4*)&hst[0][kb];
                float4 h1a = *(const float4*)&hst[1][kb];
                #pragma unroll
                for (int q = 0; q < 16; ++q) {
                    float4 h0b, h1b;
                    if (q < 15) {
                        h0b = *(const float4*)&hst[0][kb + (q + 1) * 4];
                        h1b = *(const float4*)&hst[1][kb + (q + 1) * 4];
                    }
                    p0 = fmaf(Wk[q*4+0], h0a.x, p0); p1 = fmaf(Wk[q*4+0], h1a.x, p1);
                    p0 = fmaf(Wk[q*4+1], h0a.y, p0); p1 = fmaf(Wk[q*4+1], h1a.y, p1);
                    p0 = fmaf(Wk[q*4+2], h0a.z, p0); p1 = fmaf(Wk[q*4+2], h1a.z, p1);
                    p0 = fmaf(Wk[q*4+3], h0a.w, p0); p1 = fmaf(Wk[q*4+3], h1a.w, p1);
                    if ((q & 3) == 3) __builtin_amdgcn_sched_barrier(0);
                    h0a = h0b; h1a = h1b;
                }
            }

            // speculative pre-issue for NEXT step's phase A (A(t), published
            // by wave 0 this step); self-validating
            {
                const float* a0 = &hbuf[(size_t)(t & 3) * BB * HH
                                        + (size_t)c0 * HH + kb + l];
                sA0 = __hip_atomic_load(a0,      __ATOMIC_RELAXED, __HIP_MEMORY_SCOPE_AGENT);
                sA1 = __hip_atomic_load(a0 + HH, __ATOMIC_RELAXED, __HIP_MEMORY_SCOPE_AGENT);
            }

            red[1][w][gate][0][r0] = p0;
            red[1][w][gate][1][r0] = p1;
            __syncthreads();

            if (w == 1) {   // epilogue B
                const int b = l >> 5, r = l & 31;
                float fs = 0.f, ns = 0.f;
                #pragma unroll
                for (int ww = 0; ww < 8; ++ww) {
                    fs += red[1][ww][0][b][r];
                    ns += red[1][ww][1][b][r];
                }
                float fg = __builtin_amdgcn_rcpf(1.f + __expf(-(fs + bfv)));
                float e2 = __expf(2.f * (in_cur + fg * (ns + bnv)));
                float nv = 1.f - 2.f * __builtin_amdgcn_rcpf(e2 + 1.f);
                float hn = nv + (1.f - fg) * (hprev - nv);
                hprev = hn;
                const unsigned ep = (unsigned)(((t >> 2) % 3) + 1);
                float ev = __uint_as_float((__float_as_uint(hn) & ~3u) | ep);
                float* dst = &hbuf[(size_t)(t & 3) * BB * HH
                                   + (size_t)(c0 + 2 + b) * HH + sp * 32 + r];
                __hip_atomic_store(dst, ev, __ATOMIC_RELAXED, __HIP_MEMORY_SCOPE_AGENT);
                io[obase + (size_t)t * BB * HH] = hn;
            }
        }
    }
}

// ---------------------------------------------------------------------------
extern "C" void kernel_launch(void* const* d_in, const int* in_sizes, int n_in,
                              void* d_out, int out_size, void* d_ws, size_t ws_size,
                              hipStream_t stream)
{
    const float* x   = (const float*)d_in[0];
    const float* Wih = (const float*)d_in[1];
    const float* Whh = (const float*)d_in[2];
    const float* bih = (const float*)d_in[3];
    const float* bhh = (const float*)d_in[4];
    float* io = (float*)d_out;

    float* hbuf = (float*)d_ws;   // 4 slots x 64 batches x 512 f32 = 512 KB

    // zero the slot ring: epoch bits 0 never match live epochs {1,2,3};
    // re-runs every launch/replay -> deterministic.
    hipMemsetAsync(d_ws, 0, 4 * BB * HH * 4, stream);

    in_gemm<<<dim3(16384), dim3(256), 0, stream>>>(x, Wih, bih, io);
    mgu_rec<<<dim3(256), dim3(512), 0, stream>>>(Whh, bhh, io, hbuf);
}